// Round 17
// baseline (162.688 us; speedup 1.0000x reference)
//
#include <hip/hip_runtime.h>

#define N_NODES 8192
#define D_IN 512
#define D_OUT 64
#define LRELU_ALPHA 0.2f

typedef __attribute__((ext_vector_type(8))) short bf16x8;
typedef __attribute__((ext_vector_type(4))) float f32x4;

__device__ __forceinline__ unsigned short f2bf(float x) {
    unsigned u = __float_as_uint(x);
    u += 0x7fffu + ((u >> 16) & 1u);   // round-to-nearest-even
    return (unsigned short)(u >> 16);
}

// bit-gated p: e = lrelu(wh1+w2); p = bit ? exp(e) : 0
__device__ __forceinline__ float pb(unsigned bits, int pos, float w2v, float wh1v, float& lsum) {
    float e = wh1v + w2v;
    e = fmaxf(e, LRELU_ALPHA * e);
    float p = ((bits >> pos) & 1u) ? __expf(e) : 0.f;
    lsum += p;
    return p;
}

// ---------------- Kernel 0: mask f32 (256MB) -> bitmask (8MB), vectorized (as R16) ----------------
__global__ __launch_bounds__(256) void k_maskbits(const float* __restrict__ mask,
                                                  unsigned long long* __restrict__ bits) {
    const int wave = threadIdx.x >> 6;
    const int lane = threadIdx.x & 63;
    const int row = blockIdx.x * 4 + wave;
    const float4* m4 = (const float4*)(mask + (size_t)row * N_NODES);
    const int strip = row >> 4;
    const int r16 = row & 15;
    #pragma unroll 4
    for (int q = 0; q < 32; ++q) {
        const float4 v = m4[q * 64 + lane];
        const unsigned long long b0 = __ballot(v.x > 0.f);
        const unsigned long long b1 = __ballot(v.y > 0.f);
        const unsigned long long b2 = __ballot(v.z > 0.f);
        const unsigned long long b3 = __ballot(v.w > 0.f);
        if (lane == 0) {
            unsigned long long* dst = bits + (((size_t)strip * 32 + q) * 16 + r16) * 4;
            ulonglong2 t0; t0.x = b0; t0.y = b1;
            ulonglong2 t1; t1.x = b2; t1.y = b3;
            *(ulonglong2*)(dst)     = t0;
            *(ulonglong2*)(dst + 2) = t1;
        }
    }
}

// ---------------- Kernel 1: Wh = h @ W; epilogue writes lane-local WhTp2, Wh2p, Wh1 ----------------
// WhTp2 layout (shorts): [window cc (128)][lane l=i16f+16*g (64)][frag fi=2q+h (8)][8 shorts]
//   -> consumer lane's 8 B-fragments are ONE contiguous 128B block.
// Wh2p layout (floats):  [cc][g][m][d] -> per (cc,g) the 4 W-float4s are 64B contiguous.
__global__ __launch_bounds__(256) void k_gemm_wh(const float* __restrict__ h,
                                                 const float* __restrict__ W,
                                                 const float* __restrict__ a,
                                                 unsigned short* __restrict__ WhTp2,
                                                 float* __restrict__ Wh2p,
                                                 float* __restrict__ Wh1) {
    __shared__ float hs[32][68];
    __shared__ float Ws[64][64];
    const int tid = threadIdx.x;
    const int r0 = blockIdx.x * 32;
    const int tf = tid & 15;
    const int tr = tid >> 4;
    float acc[2][4] = {{0.f,0.f,0.f,0.f},{0.f,0.f,0.f,0.f}};

    for (int kc = 0; kc < D_IN; kc += 64) {
        {
            int rr = tid >> 4;
            int cc = (tid & 15) * 4;
            float4 v0 = *(const float4*)&h[(size_t)(r0 + rr) * D_IN + kc + cc];
            float4 v1 = *(const float4*)&h[(size_t)(r0 + rr + 16) * D_IN + kc + cc];
            *(float4*)&hs[rr][cc] = v0;
            *(float4*)&hs[rr + 16][cc] = v1;
        }
        #pragma unroll
        for (int p = 0; p < 4; ++p) {
            int kk = (tid >> 4) + p * 16;
            int cc = (tid & 15) * 4;
            *(float4*)&Ws[kk][cc] = *(const float4*)&W[(size_t)(kc + kk) * D_OUT + cc];
        }
        __syncthreads();
        #pragma unroll
        for (int k = 0; k < 64; k += 4) {
            float4 a0 = *(const float4*)&hs[tr*2][k];
            float4 a1 = *(const float4*)&hs[tr*2+1][k];
            float av0[4] = {a0.x, a0.y, a0.z, a0.w};
            float av1[4] = {a1.x, a1.y, a1.z, a1.w};
            #pragma unroll
            for (int kk = 0; kk < 4; ++kk) {
                float4 b = *(const float4*)&Ws[k+kk][tf*4];
                acc[0][0] += av0[kk]*b.x; acc[0][1] += av0[kk]*b.y;
                acc[0][2] += av0[kk]*b.z; acc[0][3] += av0[kk]*b.w;
                acc[1][0] += av1[kk]*b.x; acc[1][1] += av1[kk]*b.y;
                acc[1][2] += av1[kk]*b.z; acc[1][3] += av1[kk]*b.w;
            }
        }
        __syncthreads();
    }
    const int orow = r0 + tr*2;   // even

    // lane-local WhTp2 write: cols (orow, orow+1) pack into one 4B store
    {
        const int blk = orow >> 6;
        const int cw  = orow & 63;
        const int d   = cw & 3;          // even
        const int gg  = (cw >> 2) & 3;   // k-subgroup
        const int m   = cw >> 4;
        const int hh  = m >> 1;
        const int inner = (m & 1) * 4 + d;
        #pragma unroll
        for (int k = 0; k < 4; ++k) {
            const int f = tf * 4 + k;
            const int i16f = f & 15;
            const int qf = f >> 4;
            unsigned v = (unsigned)f2bf(acc[0][k]) | ((unsigned)f2bf(acc[1][k]) << 16);
            const size_t sidx = ((size_t)(blk * 64 + i16f + 16 * gg) * 8 + 2 * qf + hh) * 8 + inner;
            *(unsigned*)&WhTp2[sidx] = v;
        }
    }

    float a1v[4], a2v[4];
    #pragma unroll
    for (int k = 0; k < 4; ++k) { a1v[k] = a[tf*4 + k]; a2v[k] = a[64 + tf*4 + k]; }
    float s1 = 0.f, t1 = 0.f, s2 = 0.f, t2 = 0.f;
    #pragma unroll
    for (int k = 0; k < 4; ++k) {
        s1 += acc[0][k] * a1v[k];
        t1 += acc[1][k] * a1v[k];
        s2 += acc[0][k] * a2v[k];
        t2 += acc[1][k] * a2v[k];
    }
    #pragma unroll
    for (int d = 1; d < 16; d <<= 1) {
        s1 += __shfl_xor(s1, d);
        t1 += __shfl_xor(t1, d);
        s2 += __shfl_xor(s2, d);
        t2 += __shfl_xor(t2, d);
    }
    if (tf == 0) {
        Wh1[orow] = s1; Wh1[orow + 1] = t1;
        const int cc0 = orow >> 6, cw0 = orow & 63;
        const int idx0 = ((cc0 * 4 + ((cw0 >> 2) & 3)) * 4 + (cw0 >> 4)) * 4 + (cw0 & 3);
        Wh2p[idx0] = s2; Wh2p[idx0 + 1] = t2;   // cw0 even -> idx0+1 is orow+1
    }
}

// ---------------- Kernel 2: bit-gated masked-softmax + PV via MFMA, line-local loads ----------------
// R16 structure (512 blocks x 8 waves, register-only loop) with the diagnosed fix: all
// per-lane loads are now LINE-LOCAL streams -- WhTp2 gives each lane its 8 B-frags in one
// contiguous 128B block (1 miss + 7 line-hits instead of 8 scattered 16KB-strided misses);
// Wh2p gives the 4 W-float4s in 64B (1 line/wave); bits already 32B-contiguous. This was
// the ~75us kernel whose loads serialized at ~200cyc each (insensitive to occupancy).
__global__ __launch_bounds__(512, 4) void k_attn(const unsigned long long* __restrict__ bits,
                                                 const unsigned short* __restrict__ WhTp2,
                                                 const float* __restrict__ Wh2p,
                                                 const float* __restrict__ Wh1,
                                                 float* __restrict__ out) {
    __shared__ float accbuf[8][16][68];
    __shared__ float lsumbuf[8][16];

    const int tid  = threadIdx.x;
    const int wave = tid >> 6;       // 0..7
    const int lane = tid & 63;
    const int i16 = lane & 15;
    const int g   = lane >> 4;
    const int R   = blockIdx.x * 16;
    const int strip = blockIdx.x;

    const float wh1v = Wh1[R + i16];
    const int sub = wave & 3;
    const int qw  = wave >> 2;
    const int sh  = sub * 16 + g;

    f32x4 acc0 = {0.f,0.f,0.f,0.f}, acc1 = {0.f,0.f,0.f,0.f};
    f32x4 acc2 = {0.f,0.f,0.f,0.f}, acc3 = {0.f,0.f,0.f,0.f};
    float lsum = 0.f;

    for (int c = 0; c < 16; ++c) {
        const int cc = c * 8 + wave;       // 64-col window
        const int q  = 2 * c + qw;         // 256-col bit group

        const unsigned long long* wp_ = bits + (((size_t)strip * 32 + q) * 16 + i16) * 4;
        const ulonglong2 Wd01 = *(const ulonglong2*)(wp_);
        const ulonglong2 Wd23 = *(const ulonglong2*)(wp_ + 2);
        const unsigned u0 = (unsigned)(Wd01.x >> sh);
        const unsigned u1 = (unsigned)(Wd01.y >> sh);
        const unsigned u2 = (unsigned)(Wd23.x >> sh);
        const unsigned u3 = (unsigned)(Wd23.y >> sh);

        // lane-local 128B: 8 consecutive 16B fragments
        const unsigned short* bb = WhTp2 + ((size_t)(cc * 64 + lane) * 8) * 8;
        const bf16x8 B0 = *(const bf16x8*)(bb);        // q0 h0
        const bf16x8 B1 = *(const bf16x8*)(bb + 8);    // q0 h1
        const bf16x8 B2 = *(const bf16x8*)(bb + 16);   // q1 h0
        const bf16x8 B3 = *(const bf16x8*)(bb + 24);   // q1 h1
        const bf16x8 B4 = *(const bf16x8*)(bb + 32);   // q2 h0
        const bf16x8 B5 = *(const bf16x8*)(bb + 40);   // q2 h1
        const bf16x8 B6 = *(const bf16x8*)(bb + 48);   // q3 h0
        const bf16x8 B7 = *(const bf16x8*)(bb + 56);   // q3 h1

        // (cc,g)-local 64B: 4 consecutive float4
        const float* wp2 = Wh2p + (size_t)(cc * 4 + g) * 16;
        const float4 W0 = *(const float4*)(wp2);
        const float4 W1 = *(const float4*)(wp2 + 4);
        const float4 W2 = *(const float4*)(wp2 + 8);
        const float4 W3 = *(const float4*)(wp2 + 12);

        // element (m, d): col = cc*64 + m*16 + g*4 + d; gate = bit 4m of u_d
        bf16x8 af0, af1;
        af0[0] = (short)f2bf(pb(u0,  0, W0.x, wh1v, lsum));
        af0[1] = (short)f2bf(pb(u1,  0, W0.y, wh1v, lsum));
        af0[2] = (short)f2bf(pb(u2,  0, W0.z, wh1v, lsum));
        af0[3] = (short)f2bf(pb(u3,  0, W0.w, wh1v, lsum));
        af0[4] = (short)f2bf(pb(u0,  4, W1.x, wh1v, lsum));
        af0[5] = (short)f2bf(pb(u1,  4, W1.y, wh1v, lsum));
        af0[6] = (short)f2bf(pb(u2,  4, W1.z, wh1v, lsum));
        af0[7] = (short)f2bf(pb(u3,  4, W1.w, wh1v, lsum));
        af1[0] = (short)f2bf(pb(u0,  8, W2.x, wh1v, lsum));
        af1[1] = (short)f2bf(pb(u1,  8, W2.y, wh1v, lsum));
        af1[2] = (short)f2bf(pb(u2,  8, W2.z, wh1v, lsum));
        af1[3] = (short)f2bf(pb(u3,  8, W2.w, wh1v, lsum));
        af1[4] = (short)f2bf(pb(u0, 12, W3.x, wh1v, lsum));
        af1[5] = (short)f2bf(pb(u1, 12, W3.y, wh1v, lsum));
        af1[6] = (short)f2bf(pb(u2, 12, W3.z, wh1v, lsum));
        af1[7] = (short)f2bf(pb(u3, 12, W3.w, wh1v, lsum));

        acc0 = __builtin_amdgcn_mfma_f32_16x16x32_bf16(af0, B0, acc0, 0, 0, 0);
        acc1 = __builtin_amdgcn_mfma_f32_16x16x32_bf16(af0, B2, acc1, 0, 0, 0);
        acc2 = __builtin_amdgcn_mfma_f32_16x16x32_bf16(af0, B4, acc2, 0, 0, 0);
        acc3 = __builtin_amdgcn_mfma_f32_16x16x32_bf16(af0, B6, acc3, 0, 0, 0);
        acc0 = __builtin_amdgcn_mfma_f32_16x16x32_bf16(af1, B1, acc0, 0, 0, 0);
        acc1 = __builtin_amdgcn_mfma_f32_16x16x32_bf16(af1, B3, acc1, 0, 0, 0);
        acc2 = __builtin_amdgcn_mfma_f32_16x16x32_bf16(af1, B5, acc2, 0, 0, 0);
        acc3 = __builtin_amdgcn_mfma_f32_16x16x32_bf16(af1, B7, acc3, 0, 0, 0);
    }

    // lsum: sum the 4 g-subgroups holding the same row
    lsum += __shfl_xor(lsum, 16);
    lsum += __shfl_xor(lsum, 32);

    // D layout (m89): row = g*4 + r, col = i16
    #pragma unroll
    for (int r = 0; r < 4; ++r) {
        accbuf[wave][g*4 + r][ 0 + i16] = acc0[r];
        accbuf[wave][g*4 + r][16 + i16] = acc1[r];
        accbuf[wave][g*4 + r][32 + i16] = acc2[r];
        accbuf[wave][g*4 + r][48 + i16] = acc3[r];
    }
    if (lane < 16) lsumbuf[wave][lane] = lsum;
    __syncthreads();

    // merge 8 waves (disjoint col-windows), normalize, ELU, store
    if (tid < 256) {
        const int tr  = tid >> 4;
        const int tf4 = (tid & 15) * 4;
        float4 s = {0.f, 0.f, 0.f, 0.f};
        float L = 0.f;
        #pragma unroll
        for (int w = 0; w < 8; ++w) {
            float4 v = *(const float4*)&accbuf[w][tr][tf4];
            s.x += v.x; s.y += v.y; s.z += v.z; s.w += v.w;
            L += lsumbuf[w][tr];
        }
        const float inv = (L > 0.f) ? 1.f / L : 0.f;
        float4 o;
        o.x = s.x * inv; o.y = s.y * inv; o.z = s.z * inv; o.w = s.w * inv;
        o.x = (o.x > 0.f) ? o.x : (__expf(o.x) - 1.f);
        o.y = (o.y > 0.f) ? o.y : (__expf(o.y) - 1.f);
        o.z = (o.z > 0.f) ? o.z : (__expf(o.z) - 1.f);
        o.w = (o.w > 0.f) ? o.w : (__expf(o.w) - 1.f);
        *(float4*)&out[(size_t)(R + tr) * D_OUT + tf4] = o;
    }
}

extern "C" void kernel_launch(void* const* d_in, const int* in_sizes, int n_in,
                              void* d_out, int out_size, void* d_ws, size_t ws_size,
                              hipStream_t stream) {
    const float* h    = (const float*)d_in[0];
    const float* mask = (const float*)d_in[1];
    // d_in[2] = lamda: unused (dischange==0 makes the mask-update a no-op)
    const float* W    = (const float*)d_in[3];
    const float* a    = (const float*)d_in[4];
    float* out = (float*)d_out;

    // ws: WhTp2 bf16 1MB | Wh2p f32 32KB | Wh1 f32 32KB | bits u64 8MB
    unsigned short* WhTp2 = (unsigned short*)d_ws;
    float* Wh2p = (float*)((char*)d_ws + (size_t)D_OUT * N_NODES * sizeof(unsigned short));
    float* Wh1 = Wh2p + N_NODES;
    unsigned long long* bitsw = (unsigned long long*)(Wh1 + N_NODES);

    k_gemm_wh<<<N_NODES / 32, 256, 0, stream>>>(h, W, a, WhTp2, Wh2p, Wh1);
    k_maskbits<<<N_NODES / 4, 256, 0, stream>>>(mask, bitsw);
    k_attn<<<N_NODES / 16, 512, 0, stream>>>(bitsw, WhTp2, Wh2p, Wh1, out);
}

// Round 18
// 105.280 us; speedup vs baseline: 1.5453x; 1.5453x over previous
//
#include <hip/hip_runtime.h>

#define N_NODES 8192
#define D_IN 512
#define D_OUT 64
#define LRELU_ALPHA 0.2f
#define KSPLIT 8
#define KSLICE (N_NODES / KSPLIT)    // 1024 cols per attn block
#define NCHUNK (KSLICE / 64)         // 16 chunks of 64 cols
#define GEMM_BLOCKS (N_NODES / 32)   // 256

typedef __attribute__((ext_vector_type(8))) short bf16x8;
typedef __attribute__((ext_vector_type(4))) float f32x4;

__device__ __forceinline__ unsigned short f2bf(float x) {
    unsigned u = __float_as_uint(x);
    u += 0x7fffu + ((u >> 16) & 1u);   // round-to-nearest-even
    return (unsigned short)(u >> 16);
}

// bit-gated p: e = lrelu(wh1+w2); p = bit ? exp(e) : 0
__device__ __forceinline__ float pb(unsigned bits, int pos, float w2v, float wh1v, float& lsum) {
    float e = wh1v + w2v;
    e = fmaxf(e, LRELU_ALPHA * e);
    float p = ((bits >> pos) & 1u) ? __expf(e) : 0.f;
    lsum += p;
    return p;
}

// ---------------- Kernel A (fused front): gemm blocks [0,256) + maskbits blocks [256,2304) ----------------
// gemm: Wh = h @ W; epilogue writes WhTp3 (bf16, block-stage order, XOR-swizzled frag slot),
//       Wh1, Wh2. maskbits: 256MB mask -> 8MB ballot bitmask (vectorized float4 loads).
// Fusing them in one dispatch overlaps gemm's compute (~14us) under the mask stream (~45us).
//
// WhTp3 layout (shorts): [window cc (128)][L (64)][slot s (8)][j (8)]
//   L = g*16 + (feat&15); s = (2*(feat>>4) + h) ^ (L&7)  (XOR -> conflict-light ds_read);
//   j = jhi*4 + jlo; element = Wh[col][feat], col = cc*64 + h*32 + jhi*16 + g*4 + jlo.
// Consumer stages the 8KB window to LDS linearly and ds_reads frag (q,h) at
//   byte addr L*128 + ((2q+h)^(L&7))*16.
__global__ __launch_bounds__(256) void k_front(const float* __restrict__ h,
                                               const float* __restrict__ W,
                                               const float* __restrict__ a,
                                               const float* __restrict__ mask,
                                               unsigned short* __restrict__ WhTp3,
                                               float* __restrict__ Wh1,
                                               float* __restrict__ Wh2,
                                               unsigned long long* __restrict__ bits) {
    __shared__ float hs[32][68];
    __shared__ float Ws[64][64];

    if (blockIdx.x >= GEMM_BLOCKS) {
        // ---------------- maskbits ----------------
        const int bid = blockIdx.x - GEMM_BLOCKS;
        const int wave = threadIdx.x >> 6;
        const int lane = threadIdx.x & 63;
        const int row = bid * 4 + wave;
        const float4* m4 = (const float4*)(mask + (size_t)row * N_NODES);
        const int strip = row >> 4;
        const int r16 = row & 15;
        #pragma unroll 4
        for (int q = 0; q < 32; ++q) {
            const float4 v = m4[q * 64 + lane];
            const unsigned long long b0 = __ballot(v.x > 0.f);
            const unsigned long long b1 = __ballot(v.y > 0.f);
            const unsigned long long b2 = __ballot(v.z > 0.f);
            const unsigned long long b3 = __ballot(v.w > 0.f);
            if (lane == 0) {
                unsigned long long* dst = bits + (((size_t)strip * 32 + q) * 16 + r16) * 4;
                ulonglong2 t0; t0.x = b0; t0.y = b1;
                ulonglong2 t1; t1.x = b2; t1.y = b3;
                *(ulonglong2*)(dst)     = t0;
                *(ulonglong2*)(dst + 2) = t1;
            }
        }
        return;
    }

    // ---------------- gemm ----------------
    const int tid = threadIdx.x;
    const int r0 = blockIdx.x * 32;
    const int tf = tid & 15;
    const int tr = tid >> 4;
    float acc[2][4] = {{0.f,0.f,0.f,0.f},{0.f,0.f,0.f,0.f}};

    for (int kc = 0; kc < D_IN; kc += 64) {
        {
            int rr = tid >> 4;
            int cc = (tid & 15) * 4;
            float4 v0 = *(const float4*)&h[(size_t)(r0 + rr) * D_IN + kc + cc];
            float4 v1 = *(const float4*)&h[(size_t)(r0 + rr + 16) * D_IN + kc + cc];
            *(float4*)&hs[rr][cc] = v0;
            *(float4*)&hs[rr + 16][cc] = v1;
        }
        #pragma unroll
        for (int p = 0; p < 4; ++p) {
            int kk = (tid >> 4) + p * 16;
            int cc = (tid & 15) * 4;
            *(float4*)&Ws[kk][cc] = *(const float4*)&W[(size_t)(kc + kk) * D_OUT + cc];
        }
        __syncthreads();
        #pragma unroll
        for (int k = 0; k < 64; k += 4) {
            float4 a0 = *(const float4*)&hs[tr*2][k];
            float4 a1 = *(const float4*)&hs[tr*2+1][k];
            float av0[4] = {a0.x, a0.y, a0.z, a0.w};
            float av1[4] = {a1.x, a1.y, a1.z, a1.w};
            #pragma unroll
            for (int kk = 0; kk < 4; ++kk) {
                float4 b = *(const float4*)&Ws[k+kk][tf*4];
                acc[0][0] += av0[kk]*b.x; acc[0][1] += av0[kk]*b.y;
                acc[0][2] += av0[kk]*b.z; acc[0][3] += av0[kk]*b.w;
                acc[1][0] += av1[kk]*b.x; acc[1][1] += av1[kk]*b.y;
                acc[1][2] += av1[kk]*b.z; acc[1][3] += av1[kk]*b.w;
            }
        }
        __syncthreads();
    }
    const int orow = r0 + tr*2;   // even

    // WhTp3 epilogue: rows (orow, orow+1) share (cc,h,g,jhi), jlo even -> one 4B store
    {
        const int cc  = orow >> 6;
        const int cw  = orow & 63;
        const int hh  = cw >> 5;
        const int rem = cw & 31;
        const int jhi = rem >> 4;
        const int gg  = (rem >> 2) & 3;
        const int jlo = cw & 3;          // even
        const int j   = jhi * 4 + jlo;
        #pragma unroll
        for (int k = 0; k < 4; ++k) {
            const int f = tf * 4 + k;
            const int L = gg * 16 + (f & 15);
            const int s = (2 * (f >> 4) + hh) ^ (L & 7);
            const size_t sidx = ((size_t)(cc * 64 + L) * 8 + s) * 8 + j;
            unsigned v = (unsigned)f2bf(acc[0][k]) | ((unsigned)f2bf(acc[1][k]) << 16);
            *(unsigned*)&WhTp3[sidx] = v;
        }
    }

    float a1v[4], a2v[4];
    #pragma unroll
    for (int k = 0; k < 4; ++k) { a1v[k] = a[tf*4 + k]; a2v[k] = a[64 + tf*4 + k]; }
    float s1 = 0.f, t1 = 0.f, s2 = 0.f, t2 = 0.f;
    #pragma unroll
    for (int k = 0; k < 4; ++k) {
        s1 += acc[0][k] * a1v[k];
        t1 += acc[1][k] * a1v[k];
        s2 += acc[0][k] * a2v[k];
        t2 += acc[1][k] * a2v[k];
    }
    #pragma unroll
    for (int d = 1; d < 16; d <<= 1) {
        s1 += __shfl_xor(s1, d);
        t1 += __shfl_xor(t1, d);
        s2 += __shfl_xor(s2, d);
        t2 += __shfl_xor(t2, d);
    }
    if (tf == 0) {
        Wh1[orow] = s1; Wh1[orow + 1] = t1;
        Wh2[orow] = s2; Wh2[orow + 1] = t2;
    }
}

// ---------------- Kernel B: bit-gated masked-softmax + PV via MFMA, block-staged B ----------------
// 512 blocks = 64 rowgroups x 8 col-slices; block = 128 rows x 1024 cols; 8 waves row-split
// (wave w owns 16-row strip). Per 64-col chunk the BLOCK stages the 8KB B-window with one
// contiguous 1KB global_load_lds per wave -> B L2-requests issued ONCE per block (1.05M
// total, vs R16's 8.4M per-wave re-reads: the diagnosed request-rate bound). Waves own
// disjoint rows -> no acc merge, no lsum merge; barriers only for B-window dbuf.
__global__ __launch_bounds__(512, 4) void k_attn(const unsigned long long* __restrict__ bits,
                                                 const unsigned short* __restrict__ WhTp3,
                                                 const float* __restrict__ Wh1,
                                                 const float* __restrict__ Wh2,
                                                 float* __restrict__ pacc,
                                                 float* __restrict__ plsum) {
    __shared__ unsigned short bbuf[2][4096];   // 2 x 8KB B-window double buffer

    const int tid  = threadIdx.x;
    const int wave = tid >> 6;       // 0..7: strip within rowgroup
    const int lane = tid & 63;
    const int i16 = lane & 15;
    const int g   = lane >> 4;
    const int rg    = blockIdx.x >> 3;
    const int slice = blockIdx.x & 7;
    const int Rw    = rg * 128 + wave * 16;     // this wave's 16 rows
    const int strip = rg * 8 + wave;            // global 16-row strip index
    const int ccbase = slice * NCHUNK;          // first 64-col window

    const float wh1v = Wh1[Rw + i16];

    f32x4 acc0 = {0.f,0.f,0.f,0.f}, acc1 = {0.f,0.f,0.f,0.f};
    f32x4 acc2 = {0.f,0.f,0.f,0.f}, acc3 = {0.f,0.f,0.f,0.f};
    float lsum = 0.f;

    // stage chunk c's 8KB B-window: one contiguous 1KB DMA per wave (linear dest, m104)
#define STAGE(c, par)                                                                   \
    {                                                                                   \
        const unsigned short* src = WhTp3 + ((size_t)(ccbase + (c)) * 512 + wave * 64 + lane) * 8; \
        __builtin_amdgcn_global_load_lds(src, &bbuf[par][wave * 512], 16, 0, 0);        \
    }

    STAGE(0, 0);
    __syncthreads();

    #pragma unroll 2
    for (int c = 0; c < NCHUNK; ++c) {
        const int par = c & 1;
        const int cc = ccbase + c;

        if (c + 1 < NCHUNK) STAGE(c + 1, par ^ 1);

        // bits for this wave's strip (32B per lane-group, L2)
        const int q   = cc >> 2;
        const int sub = cc & 3;
        const int sh  = sub * 16 + g;
        const unsigned long long* wp_ = bits + (((size_t)strip * 32 + q) * 16 + i16) * 4;
        const ulonglong2 Wd01 = *(const ulonglong2*)(wp_);
        const ulonglong2 Wd23 = *(const ulonglong2*)(wp_ + 2);
        const unsigned u0 = (unsigned)(Wd01.x >> sh);
        const unsigned u1 = (unsigned)(Wd01.y >> sh);
        const unsigned u2 = (unsigned)(Wd23.x >> sh);
        const unsigned u3 = (unsigned)(Wd23.y >> sh);

        // Wh2 for the window (tiny, L2)
        const float* wp = Wh2 + cc * 64 + g * 4;
        const float4 W0 = *(const float4*)(wp);
        const float4 W1 = *(const float4*)(wp + 16);
        const float4 W2 = *(const float4*)(wp + 32);
        const float4 W3 = *(const float4*)(wp + 48);

        // B frags from LDS: lane base L*128 bytes, slot (2q+h)^(L&7)
        const unsigned short* lb = &bbuf[par][lane * 64];
        const bf16x8 B00 = *(const bf16x8*)(lb + ((0 ^ (lane & 7)) * 8));
        const bf16x8 B01 = *(const bf16x8*)(lb + ((1 ^ (lane & 7)) * 8));
        const bf16x8 B10 = *(const bf16x8*)(lb + ((2 ^ (lane & 7)) * 8));
        const bf16x8 B11 = *(const bf16x8*)(lb + ((3 ^ (lane & 7)) * 8));
        const bf16x8 B20 = *(const bf16x8*)(lb + ((4 ^ (lane & 7)) * 8));
        const bf16x8 B21 = *(const bf16x8*)(lb + ((5 ^ (lane & 7)) * 8));
        const bf16x8 B30 = *(const bf16x8*)(lb + ((6 ^ (lane & 7)) * 8));
        const bf16x8 B31 = *(const bf16x8*)(lb + ((7 ^ (lane & 7)) * 8));

        // element (m, d): col = cc*64 + m*16 + g*4 + d; gate = bit 4m of u_d
        bf16x8 af0, af1;
        af0[0] = (short)f2bf(pb(u0,  0, W0.x, wh1v, lsum));
        af0[1] = (short)f2bf(pb(u1,  0, W0.y, wh1v, lsum));
        af0[2] = (short)f2bf(pb(u2,  0, W0.z, wh1v, lsum));
        af0[3] = (short)f2bf(pb(u3,  0, W0.w, wh1v, lsum));
        af0[4] = (short)f2bf(pb(u0,  4, W1.x, wh1v, lsum));
        af0[5] = (short)f2bf(pb(u1,  4, W1.y, wh1v, lsum));
        af0[6] = (short)f2bf(pb(u2,  4, W1.z, wh1v, lsum));
        af0[7] = (short)f2bf(pb(u3,  4, W1.w, wh1v, lsum));
        af1[0] = (short)f2bf(pb(u0,  8, W2.x, wh1v, lsum));
        af1[1] = (short)f2bf(pb(u1,  8, W2.y, wh1v, lsum));
        af1[2] = (short)f2bf(pb(u2,  8, W2.z, wh1v, lsum));
        af1[3] = (short)f2bf(pb(u3,  8, W2.w, wh1v, lsum));
        af1[4] = (short)f2bf(pb(u0, 12, W3.x, wh1v, lsum));
        af1[5] = (short)f2bf(pb(u1, 12, W3.y, wh1v, lsum));
        af1[6] = (short)f2bf(pb(u2, 12, W3.z, wh1v, lsum));
        af1[7] = (short)f2bf(pb(u3, 12, W3.w, wh1v, lsum));

        acc0 = __builtin_amdgcn_mfma_f32_16x16x32_bf16(af0, B00, acc0, 0, 0, 0);
        acc1 = __builtin_amdgcn_mfma_f32_16x16x32_bf16(af0, B10, acc1, 0, 0, 0);
        acc2 = __builtin_amdgcn_mfma_f32_16x16x32_bf16(af0, B20, acc2, 0, 0, 0);
        acc3 = __builtin_amdgcn_mfma_f32_16x16x32_bf16(af0, B30, acc3, 0, 0, 0);
        acc0 = __builtin_amdgcn_mfma_f32_16x16x32_bf16(af1, B01, acc0, 0, 0, 0);
        acc1 = __builtin_amdgcn_mfma_f32_16x16x32_bf16(af1, B11, acc1, 0, 0, 0);
        acc2 = __builtin_amdgcn_mfma_f32_16x16x32_bf16(af1, B21, acc2, 0, 0, 0);
        acc3 = __builtin_amdgcn_mfma_f32_16x16x32_bf16(af1, B31, acc3, 0, 0, 0);

        if (c + 1 < NCHUNK) __syncthreads();   // STAGE(c+1) drained; bbuf[par] free for c+2
    }
#undef STAGE

    // per-row lsum: combine the 4 g-subgroups (xor 16/32 varies g only)
    lsum += __shfl_xor(lsum, 16);
    lsum += __shfl_xor(lsum, 32);

    // D layout (m89): row = g*4 + r (within strip), feature = q*16 + i16; rows are
    // wave-private -> direct partial writes, no cross-wave merge.
    #pragma unroll
    for (int r = 0; r < 4; ++r) {
        const int row = Rw + g * 4 + r;
        float* pr = pacc + ((size_t)slice * N_NODES + row) * D_OUT + i16;
        pr[ 0] = acc0[r];
        pr[16] = acc1[r];
        pr[32] = acc2[r];
        pr[48] = acc3[r];
    }
    if (lane < 16) plsum[(size_t)slice * N_NODES + Rw + lane] = lsum;
}

// ---------------- Kernel C: sum KSPLIT partials, normalize, ELU ----------------
__global__ __launch_bounds__(256) void k_finish(const float* __restrict__ pacc,
                                                const float* __restrict__ plsum,
                                                float* __restrict__ out) {
    const int idx = blockIdx.x * 256 + threadIdx.x;
    const int row = idx >> 4;
    const int tf4 = (idx & 15) * 4;
    float4 s = {0.f, 0.f, 0.f, 0.f};
    float L = 0.f;
    #pragma unroll
    for (int k = 0; k < KSPLIT; ++k) {
        float4 v = *(const float4*)&pacc[((size_t)k * N_NODES + row) * D_OUT + tf4];
        s.x += v.x; s.y += v.y; s.z += v.z; s.w += v.w;
        L += plsum[(size_t)k * N_NODES + row];
    }
    const float inv = (L > 0.f) ? 1.f / L : 0.f;
    float4 o;
    o.x = s.x * inv; o.y = s.y * inv; o.z = s.z * inv; o.w = s.w * inv;
    o.x = (o.x > 0.f) ? o.x : (__expf(o.x) - 1.f);
    o.y = (o.y > 0.f) ? o.y : (__expf(o.y) - 1.f);
    o.z = (o.z > 0.f) ? o.z : (__expf(o.z) - 1.f);
    o.w = (o.w > 0.f) ? o.w : (__expf(o.w) - 1.f);
    *(float4*)&out[(size_t)row * D_OUT + tf4] = o;
}

extern "C" void kernel_launch(void* const* d_in, const int* in_sizes, int n_in,
                              void* d_out, int out_size, void* d_ws, size_t ws_size,
                              hipStream_t stream) {
    const float* h    = (const float*)d_in[0];
    const float* mask = (const float*)d_in[1];
    // d_in[2] = lamda: unused (dischange==0 makes the mask-update a no-op)
    const float* W    = (const float*)d_in[3];
    const float* a    = (const float*)d_in[4];
    float* out = (float*)d_out;

    // ws: WhTp3 1MB | Wh1 32KB | Wh2 32KB | bits 8MB | pacc 16MB | plsum 256KB
    unsigned short* WhTp3 = (unsigned short*)d_ws;
    float* Wh1 = (float*)((char*)d_ws + (size_t)D_OUT * N_NODES * sizeof(unsigned short));
    float* Wh2 = Wh1 + N_NODES;
    unsigned long long* bitsw = (unsigned long long*)(Wh2 + N_NODES);
    float* pacc = (float*)(bitsw + (size_t)N_NODES * (N_NODES / 64));
    float* plsum = pacc + (size_t)KSPLIT * N_NODES * D_OUT;

    k_front<<<GEMM_BLOCKS + N_NODES / 4, 256, 0, stream>>>(h, W, a, mask, WhTp3, Wh1, Wh2, bitsw);
    k_attn<<<(N_NODES / 128) * KSPLIT, 512, 0, stream>>>(bitsw, WhTp3, Wh1, Wh2, pacc, plsum);
    k_finish<<<(N_NODES * D_OUT / 4) / 256, 256, 0, stream>>>(pacc, plsum, out);
}